// Round 12
// baseline (205.588 us; speedup 1.0000x reference)
//
#include <hip/hip_runtime.h>
#include <hip/hip_bf16.h>

#define BLOCK   512     // 8 waves; wave w owns channels w*16..w*16+15, all 4 gates
#define NSAMP   16
#define HDIM    128
#define DDIM    16
#define NOBJ    6
#define NSLOT   14

typedef __attribute__((ext_vector_type(8))) short bf16x8;
typedef __attribute__((ext_vector_type(4))) float f32x4;

constexpr int pc6(int m)  { int c = 0; for (int i = 0; i < 6; ++i) c += (m >> i) & 1; return c; }
constexpr int msb6(int m) { int b = -1; for (int i = 0; i < 6; ++i) if (m & (1 << i)) b = i; return b; }

// Compile-time BFS plan, 14-slot allocator with multi-phase recycling (verified R11).
struct PNode { int jo, ps, sl; bool bar; };
struct Plan2 { PNode nd[63]; int lvlStart[8]; };
constexpr Plan2 make_plan2() {
    Plan2 P{};
    int slotOf[64] = {};
    bool busy[NSLOT] = {};
    int k = 0;
    for (int d = 1; d <= 6; ++d) {
        P.lvlStart[d] = k;
        for (int M = 1; M < 64; ++M) {               // leaves (msb==5): no slot
            if (pc6(M) != d || msb6(M) != 5) continue;
            P.nd[k].jo = 5;
            P.nd[k].ps = (d == 1) ? -1 : slotOf[M & ~(1 << 5)];
            P.nd[k].sl = -1;
            P.nd[k].bar = false;
            ++k;
        }
        int pend[20] = {}; int np = 0;
        for (int M = 1; M < 64; ++M)
            if (pc6(M) == d && msb6(M) < 5) pend[np++] = M;
        int key[20] = {};
        for (int i = 0; i < np; ++i) {
            if (d == 1) { key[i] = 0; continue; }
            const int par = pend[i] & ~(1 << msb6(pend[i]));
            int c2 = 0;
            for (int j2 = 0; j2 < np; ++j2)
                if ((pend[j2] & ~(1 << msb6(pend[j2]))) == par) ++c2;
            key[i] = c2;
        }
        for (int a = 0; a < np; ++a)
            for (int b2 = a + 1; b2 < np; ++b2)
                if (key[b2] < key[a]) {
                    int tm = key[a]; key[a] = key[b2]; key[b2] = tm;
                    tm = pend[a]; pend[a] = pend[b2]; pend[b2] = tm;
                }
        bool placed[20] = {};
        int nplaced = 0;
        bool firstPhase = true;
        while (nplaced < np) {
            bool needBar = !firstPhase;
            bool any = false;
            for (int i = 0; i < np; ++i) {
                if (placed[i]) continue;
                int fs = -1;
                for (int s = 0; s < NSLOT; ++s) if (!busy[s]) { fs = s; break; }
                if (fs < 0) break;
                const int M = pend[i]; const int hi = msb6(M);
                busy[fs] = true; slotOf[M] = fs;
                P.nd[k].jo = hi;
                P.nd[k].ps = (d == 1) ? -1 : slotOf[M & ~(1 << hi)];
                P.nd[k].sl = fs;
                P.nd[k].bar = needBar; needBar = false;
                ++k; placed[i] = true; ++nplaced; any = true;
            }
            firstPhase = false;
            if (nplaced < np) {
                if (!any) break;
                for (int M = 1; M < 64; ++M) {
                    if (pc6(M) != d - 1 || msb6(M) >= 5) continue;
                    bool allp = true;
                    for (int i = 0; i < np; ++i)
                        if (!placed[i] &&
                            ((pend[i] & ~(1 << msb6(pend[i]))) == M)) allp = false;
                    if (allp) busy[slotOf[M]] = false;
                }
            }
        }
        for (int s = 0; s < NSLOT; ++s) busy[s] = false;
        for (int M = 1; M < 64; ++M)
            if (pc6(M) == d && msb6(M) < 5) busy[slotOf[M]] = true;
    }
    P.lvlStart[7] = k;
    return P;
}
constexpr Plan2 PL2 = make_plan2();
static_assert(PL2.lvlStart[7] == 63, "plan must cover all 63 nodes");

#define LOG2E   1.44269504f
#define TWOL2E  2.88539008f
#define SLOT_SH 2048            // shorts per slot (4 KB), both h and c pools

__device__ __forceinline__ unsigned short f2bf(float x) {
    union { float f; unsigned int u; } a; a.f = x;
    unsigned int r = (a.u + 0x7FFFu + ((a.u >> 16) & 1u)) >> 16;
    return (unsigned short)r;
}
__device__ __forceinline__ unsigned pk2(float a, float b) {
    union { __hip_bfloat162 h; unsigned u; } z;
    z.h = __float22bfloat162_rn(float2{a, b});
    return z.u;
}
__device__ __forceinline__ float bflo(unsigned p) {
    union { unsigned u; float f; } a; a.u = p << 16; return a.f;
}
__device__ __forceinline__ float bfhi(unsigned p) {
    union { unsigned u; float f; } a; a.u = p & 0xFFFF0000u; return a.f;
}

// h pool: hs[((slot*16 + kslot)*NSAMP + n)*8 + j] = h[ch = kslot*8+j][sample n]
//   B-frag chunk q, lane (quad,m16): kslot = q*4+quad -> 16B-aligned ds_read_b128
//   wave w writes ch = w*16+quad*4+r at kslot = w*2+(quad>>1), j = (quad&1)*4+r
// c pool: csb[((slot*32 + w*4+quad)*NSAMP + n)*4 + r], bf16 (b64/lane, conflict-free)

__global__ __launch_bounds__(BLOCK)
__attribute__((amdgpu_waves_per_eu(2, 2)))   // pin 256-VGPR budget, no heuristic spill (R8-verified)
void subset_lstm_xz_kernel(
    const float* __restrict__ x_input,
    const float* __restrict__ W_ih,
    const float* __restrict__ W_hh,
    const float* __restrict__ b_ih,
    const float* __restrict__ b_hh,
    const float* __restrict__ fc1_W,
    const float* __restrict__ fc1_b,
    const float* __restrict__ fc2_W,
    const float* __restrict__ fc2_b,
    float* __restrict__ out)
{
    __shared__ __align__(16) unsigned short hs [NSLOT * SLOT_SH];       // 56 KB
    __shared__ __align__(16) unsigned short csb[NSLOT * SLOT_SH];       // 56 KB
    __shared__ __align__(16) unsigned short xb[NOBJ * 4 * NSAMP * 8];   // 6 KB
    float* s_maxh  = (float*)hs;                 // 8 KB  (post-LSTM alias)
    float* s_fc1   = (float*)(hs + 4096);        // 16 KB (post-LSTM alias)
    float* s_logit = (float*)xb;

    const int t      = threadIdx.x;
    const int w      = t >> 6;
    const int lane   = t & 63;
    const int quad   = lane >> 4;
    const int m16    = lane & 15;
    const int s_base = blockIdx.x * NSAMP;

    // ---- x B-chunks: xb[obj][quad'][n][j]; quad2 j0 = 1.0 (bias lane), quad3 zero ----
    for (int idx = t; idx < NOBJ * 4 * NSAMP * 8; idx += BLOCK) {
        const int j = idx & 7, n = (idx >> 3) & 15, q = (idx >> 7) & 3, obj = idx >> 9;
        float v;
        if (q < 2) v = x_input[(s_base + n) * (NOBJ * DDIM) + obj * DDIM + q * 8 + j];
        else       v = (q == 2 && j == 0) ? 1.0f : 0.0f;
        xb[idx] = f2bf(v);
    }

    // ---- persistent A-frags wf[gate][chunk 0..3] (h-part only, PRE-SCALED) ----
    bf16x8 wf[4][4];
    #pragma unroll
    for (int g = 0; g < 4; ++g) {
        const float sc = (g == 2) ? TWOL2E : -LOG2E;
        const int grow = g * HDIM + w * 16 + m16;
        const float* whr = W_hh + grow * HDIM;
        #pragma unroll
        for (int q = 0; q < 4; ++q) {
            union { unsigned short u[8]; bf16x8 v; } pk;
            #pragma unroll
            for (int j = 0; j < 8; ++j)
                pk.u[j] = f2bf(sc * whr[q * 32 + quad * 8 + j]);
            wf[g][q] = pk.v;
        }
    }

    __syncthreads();   // xb staged

    // ---- precompute xz[obj][gate] = sc*(W_ih x_obj + b), held in VGPRs (96) ----
    f32x4 xz[NOBJ][4];
    {
        bf16x8 bfx[NOBJ];
        #pragma unroll
        for (int o = 0; o < NOBJ; ++o)
            bfx[o] = *(const bf16x8*)&xb[((o * 4 + quad) * NSAMP + m16) * 8];
        const f32x4 fz = {0.f, 0.f, 0.f, 0.f};
        #pragma unroll
        for (int g = 0; g < 4; ++g) {
            const float sc = (g == 2) ? TWOL2E : -LOG2E;
            const int grow = g * HDIM + w * 16 + m16;
            const float* wir = W_ih + grow * DDIM;
            union { unsigned short u[8]; bf16x8 v; } pk;   // transient x-chunk A-frag
            #pragma unroll
            for (int j = 0; j < 8; ++j) {
                float v = 0.0f;
                if (quad < 2) v = sc * wir[quad * 8 + j];
                else if (quad == 2 && j == 0) v = sc * (b_ih[grow] + b_hh[grow]);
                pk.u[j] = f2bf(v);
            }
            #pragma unroll
            for (int o = 0; o < NOBJ; ++o)
                xz[o][g] = __builtin_amdgcn_mfma_f32_16x16x32_bf16(
                    pk.v, bfx[o], fz, 0, 0, 0);
        }
    }

    float mh[4] = {-1e30f, -1e30f, -1e30f, -1e30f};
    const int kslot = w * 2 + (quad >> 1);
    unsigned short* const c_lane = &csb[(((w * 4 + quad) * NSAMP) + m16) * 4];

    #pragma unroll
    for (int d = 1; d <= 6; ++d) {
        __syncthreads();
        #pragma unroll
        for (int k = PL2.lvlStart[d]; k < PL2.lvlStart[d + 1]; ++k) {
            if (PL2.nd[k].bar) __syncthreads();   // intra-level recycle barrier (constexpr)
            const int jo = PL2.nd[k].jo;
            const int ps = PL2.nd[k].ps;
            const int sl = PL2.nd[k].sl;

            float cp[4] = {0.f, 0.f, 0.f, 0.f};
            f32x4 acc[4];
            if (ps >= 0) {
                const uint2 cpk = *(const uint2*)(c_lane + ps * SLOT_SH);
                cp[0] = bflo(cpk.x); cp[1] = bfhi(cpk.x);
                cp[2] = bflo(cpk.y); cp[3] = bfhi(cpk.y);
                // h chunks, C-seeded by xz[jo] (no x-MFMA, no acc-init)
                {
                    const bf16x8 bh = *(const bf16x8*)
                        &hs[((ps * 16 + 0 * 4 + quad) * NSAMP + m16) * 8];
                    #pragma unroll
                    for (int g = 0; g < 4; ++g)
                        acc[g] = __builtin_amdgcn_mfma_f32_16x16x32_bf16(
                            wf[g][0], bh, xz[jo][g], 0, 0, 0);
                }
                #pragma unroll
                for (int q = 1; q < 4; ++q) {
                    const bf16x8 bh = *(const bf16x8*)
                        &hs[((ps * 16 + q * 4 + quad) * NSAMP + m16) * 8];
                    #pragma unroll
                    for (int g = 0; g < 4; ++g)
                        acc[g] = __builtin_amdgcn_mfma_f32_16x16x32_bf16(
                            wf[g][q], bh, acc[g], 0, 0, 0);
                }
            } else {
                #pragma unroll
                for (int g = 0; g < 4; ++g) acc[g] = xz[jo][g];
            }

            // fused pointwise (verified R9-R11): ch = w*16+quad*4+r, sample m16
            float cn4[4], hn4[4];
            #pragma unroll
            for (int r = 0; r < 4; ++r) {
                const float u  = 1.0f + __builtin_amdgcn_exp2f(acc[0][r]);
                const float q  = 1.0f + __builtin_amdgcn_exp2f(acc[1][r]);
                const float v  = 1.0f + __builtin_amdgcn_exp2f(acc[2][r]);
                const float qo = 1.0f + __builtin_amdgcn_exp2f(acc[3][r]);
                const float uv  = u * v;
                const float num = fmaf(q, v - 2.0f, cp[r] * uv);
                const float cn  = num * __builtin_amdgcn_rcpf(q * uv);
                const float wt  = 1.0f + __builtin_amdgcn_exp2f(TWOL2E * cn);
                const float h   = (wt - 2.0f) * __builtin_amdgcn_rcpf(qo * wt);
                cn4[r] = cn; hn4[r] = h;
                mh[r] = fmaxf(mh[r], h);
            }

            if (sl >= 0) {   // childful: publish c (bf16 LDS) and h (B-layout LDS)
                uint2 cw; cw.x = pk2(cn4[0], cn4[1]); cw.y = pk2(cn4[2], cn4[3]);
                *(uint2*)(c_lane + sl * SLOT_SH) = cw;
                uint2 hw; hw.x = pk2(hn4[0], hn4[1]); hw.y = pk2(hn4[2], hn4[3]);
                *(uint2*)&hs[((sl * 16 + kslot) * NSAMP + m16) * 8
                             + (quad & 1) * 4] = hw;
            }
        }
    }

    __syncthreads();   // pools dead; reuse hs for epilogue
    {
        float4 v; v.x = mh[0]; v.y = mh[1]; v.z = mh[2]; v.w = mh[3];
        *(float4*)&s_maxh[m16 * HDIM + w * 16 + quad * 4] = v;
    }
    __syncthreads();

    // ---- FC1: f = t&255, sample half t>>8 (8 samples each) ----
    {
        const int f  = t & 255;
        const int sh = t >> 8;
        float a1[8];
        #pragma unroll
        for (int s = 0; s < 8; ++s) a1[s] = fc1_b[f];
        for (int k4 = 0; k4 < HDIM / 4; ++k4) {
            const float4 wv = *(const float4*)&fc1_W[f * HDIM + k4 * 4];
            #pragma unroll
            for (int s = 0; s < 8; ++s) {
                const float4 h4 = *(const float4*)&s_maxh[(sh * 8 + s) * HDIM + k4 * 4];
                a1[s] += wv.x * h4.x + wv.y * h4.y + wv.z * h4.z + wv.w * h4.w;
            }
        }
        #pragma unroll
        for (int s = 0; s < 8; ++s)
            s_fc1[(sh * 8 + s) * 256 + f] = fmaxf(a1[s], 0.0f);
    }
    __syncthreads();

    if (t < NSAMP * 10) {
        const int s = t / 10, a = t % 10;
        float acc2 = fc2_b[a];
        for (int f4 = 0; f4 < 256 / 4; ++f4) {
            const float4 wv = *(const float4*)&fc2_W[a * 256 + f4 * 4];
            const float4 v  = *(const float4*)&s_fc1[s * 256 + f4 * 4];
            acc2 += wv.x * v.x + wv.y * v.y + wv.z * v.z + wv.w * v.w;
        }
        s_logit[s * 10 + a] = acc2;
    }
    __syncthreads();

    if (t < NSAMP) {
        float m = -1e30f;
        #pragma unroll
        for (int a = 0; a < 10; ++a) m = fmaxf(m, s_logit[t * 10 + a]);
        float sum = 0.0f;
        #pragma unroll
        for (int a = 0; a < 10; ++a) sum += __expf(s_logit[t * 10 + a] - m);
        const float lse = m + __logf(sum);
        #pragma unroll
        for (int a = 0; a < 10; ++a)
            out[(s_base + t) * 10 + a] = s_logit[t * 10 + a] - lse;
    }
}

extern "C" void kernel_launch(void* const* d_in, const int* in_sizes, int n_in,
                              void* d_out, int out_size, void* d_ws, size_t ws_size,
                              hipStream_t stream)
{
    (void)d_ws; (void)ws_size; (void)n_in; (void)out_size;

    const float* x   = (const float*)d_in[0];
    const float* Wih = (const float*)d_in[1];
    const float* Whh = (const float*)d_in[2];
    const float* bih = (const float*)d_in[3];
    const float* bhh = (const float*)d_in[4];
    const float* f1w = (const float*)d_in[5];
    const float* f1b = (const float*)d_in[6];
    const float* f2w = (const float*)d_in[7];
    const float* f2b = (const float*)d_in[8];

    const int mb = in_sizes[0] / (NOBJ * DDIM);   // 8192
    dim3 grid(mb / NSAMP), block(BLOCK);
    subset_lstm_xz_kernel<<<grid, block, 0, stream>>>(
        x, Wih, Whh, bih, bhh, f1w, f1b, f2w, f2b, (float*)d_out);
}

// Round 13
// 195.661 us; speedup vs baseline: 1.0507x; 1.0507x over previous
//
#include <hip/hip_runtime.h>
#include <hip/hip_bf16.h>

#define BLOCK   512     // 8 waves; wave w owns channels w*16..w*16+15, all 4 gates
#define NSAMP   16
#define HDIM    128
#define DDIM    16
#define NOBJ    6
#define NSLOT   14      // h slot pool: 56 KB -> total LDS < 64 KB

typedef __attribute__((ext_vector_type(8))) short bf16x8;
typedef __attribute__((ext_vector_type(4))) float f32x4;

constexpr int pc6(int m)  { int c = 0; for (int i = 0; i < 6; ++i) c += (m >> i) & 1; return c; }
constexpr int msb6(int m) { int b = -1; for (int i = 0; i < 6; ++i) if (m & (1 << i)) b = i; return b; }

// Compile-time BFS plan, 14-slot allocator with multi-phase recycling (verified R11).
struct PNode { int jo, ps, sl; bool bar; };
struct Plan2 { PNode nd[63]; int lvlStart[8]; };
constexpr Plan2 make_plan2() {
    Plan2 P{};
    int slotOf[64] = {};
    bool busy[NSLOT] = {};
    int k = 0;
    for (int d = 1; d <= 6; ++d) {
        P.lvlStart[d] = k;
        for (int M = 1; M < 64; ++M) {               // leaves (msb==5): no slot
            if (pc6(M) != d || msb6(M) != 5) continue;
            P.nd[k].jo = 5;
            P.nd[k].ps = (d == 1) ? -1 : slotOf[M & ~(1 << 5)];
            P.nd[k].sl = -1;
            P.nd[k].bar = false;
            ++k;
        }
        int pend[20] = {}; int np = 0;
        for (int M = 1; M < 64; ++M)
            if (pc6(M) == d && msb6(M) < 5) pend[np++] = M;
        int key[20] = {};
        for (int i = 0; i < np; ++i) {
            if (d == 1) { key[i] = 0; continue; }
            const int par = pend[i] & ~(1 << msb6(pend[i]));
            int c2 = 0;
            for (int j2 = 0; j2 < np; ++j2)
                if ((pend[j2] & ~(1 << msb6(pend[j2]))) == par) ++c2;
            key[i] = c2;
        }
        for (int a = 0; a < np; ++a)
            for (int b2 = a + 1; b2 < np; ++b2)
                if (key[b2] < key[a]) {
                    int tm = key[a]; key[a] = key[b2]; key[b2] = tm;
                    tm = pend[a]; pend[a] = pend[b2]; pend[b2] = tm;
                }
        bool placed[20] = {};
        int nplaced = 0;
        bool firstPhase = true;
        while (nplaced < np) {
            bool needBar = !firstPhase;
            bool any = false;
            for (int i = 0; i < np; ++i) {
                if (placed[i]) continue;
                int fs = -1;
                for (int s = 0; s < NSLOT; ++s) if (!busy[s]) { fs = s; break; }
                if (fs < 0) break;
                const int M = pend[i]; const int hi = msb6(M);
                busy[fs] = true; slotOf[M] = fs;
                P.nd[k].jo = hi;
                P.nd[k].ps = (d == 1) ? -1 : slotOf[M & ~(1 << hi)];
                P.nd[k].sl = fs;
                P.nd[k].bar = needBar; needBar = false;
                ++k; placed[i] = true; ++nplaced; any = true;
            }
            firstPhase = false;
            if (nplaced < np) {
                if (!any) break;
                for (int M = 1; M < 64; ++M) {
                    if (pc6(M) != d - 1 || msb6(M) >= 5) continue;
                    bool allp = true;
                    for (int i = 0; i < np; ++i)
                        if (!placed[i] &&
                            ((pend[i] & ~(1 << msb6(pend[i]))) == M)) allp = false;
                    if (allp) busy[slotOf[M]] = false;
                }
            }
        }
        for (int s = 0; s < NSLOT; ++s) busy[s] = false;
        for (int M = 1; M < 64; ++M)
            if (pc6(M) == d && msb6(M) < 5) busy[slotOf[M]] = true;
    }
    P.lvlStart[7] = k;
    return P;
}
constexpr Plan2 PL2 = make_plan2();
static_assert(PL2.lvlStart[7] == 63, "plan must cover all 63 nodes");

// Pair table: adjacent same-level nodes grouped 2-at-a-time; never spans a
// barrier (2nd member must have bar==false). Group inherits 1st member's bar.
struct Groups { int cnt[7]; int a[7][20]; int b[7][20]; bool bar[7][20]; };
constexpr Groups make_groups() {
    Groups G{};
    for (int d = 1; d <= 6; ++d) {
        int gi = 0;
        int k = PL2.lvlStart[d];
        const int e = PL2.lvlStart[d + 1];
        while (k < e) {
            G.a[d][gi] = k;
            G.bar[d][gi] = PL2.nd[k].bar;
            if (k + 1 < e && !PL2.nd[k + 1].bar) { G.b[d][gi] = k + 1; k += 2; }
            else                                 { G.b[d][gi] = -1;    k += 1; }
            ++gi;
        }
        G.cnt[d] = gi;
    }
    return G;
}
constexpr Groups GR = make_groups();

#define LOG2E   1.44269504f
#define TWOL2E  2.88539008f
#define SLOT_SH 2048            // shorts per slot (4 KB)

__device__ __forceinline__ unsigned short f2bf(float x) {
    union { float f; unsigned int u; } a; a.f = x;
    unsigned int r = (a.u + 0x7FFFu + ((a.u >> 16) & 1u)) >> 16;
    return (unsigned short)r;
}
__device__ __forceinline__ unsigned pk2(float a, float b) {
    union { __hip_bfloat162 h; unsigned u; } z;
    z.h = __float22bfloat162_rn(float2{a, b});
    return z.u;
}
__device__ __forceinline__ float bflo(unsigned p) {
    union { unsigned u; float f; } a; a.u = p << 16; return a.f;
}
__device__ __forceinline__ float bfhi(unsigned p) {
    union { unsigned u; float f; } a; a.u = p & 0xFFFF0000u; return a.f;
}

// LDS h layout: hs[((slot*16 + kslot)*NSAMP + n)*8 + j] = h[ch = kslot*8+j][sample n]
// B-frag chunk q, lane (quad,m16): kslot = q*4+quad -> 16B-aligned ds_read_b128.
// Wave w writes ch = w*16+quad*4+r at kslot = w*2+(quad>>1), j = (quad&1)*4+r.

__global__ __launch_bounds__(BLOCK)
__attribute__((amdgpu_waves_per_eu(2, 4)))   // R11-verified: VGPR 128, no spill
void subset_lstm_p14_kernel(
    const float* __restrict__ x_input,
    const float* __restrict__ W_ih,
    const float* __restrict__ W_hh,
    const float* __restrict__ b_ih,
    const float* __restrict__ b_hh,
    const float* __restrict__ fc1_W,
    const float* __restrict__ fc1_b,
    const float* __restrict__ fc2_W,
    const float* __restrict__ fc2_b,
    float* __restrict__ out)
{
    __shared__ __align__(16) unsigned short hs[NSLOT * SLOT_SH];        // 56 KB
    __shared__ __align__(16) unsigned short xb[NOBJ * 4 * NSAMP * 8];   // 6 KB
    float* s_maxh  = (float*)hs;                 // 8 KB  (post-LSTM alias)
    float* s_fc1   = (float*)(hs + 4096);        // 16 KB (post-LSTM alias)
    float* s_logit = (float*)xb;

    const int t      = threadIdx.x;
    const int w      = t >> 6;
    const int lane   = t & 63;
    const int quad   = lane >> 4;
    const int m16    = lane & 15;
    const int s_base = blockIdx.x * NSAMP;

    // ---- x B-chunks: xb[obj][quad'][n][j]; quad2 j0 = 1.0 (bias lane), quad3 zero ----
    for (int idx = t; idx < NOBJ * 4 * NSAMP * 8; idx += BLOCK) {
        const int j = idx & 7, n = (idx >> 3) & 15, q = (idx >> 7) & 3, obj = idx >> 9;
        float v;
        if (q < 2) v = x_input[(s_base + n) * (NOBJ * DDIM) + obj * DDIM + q * 8 + j];
        else       v = (q == 2 && j == 0) ? 1.0f : 0.0f;
        xb[idx] = f2bf(v);
    }

    // ---- persistent A-frags wf[gate][chunk], PRE-SCALED (verified R8-R11) ----
    // gates i,f,o: row *= -log2e ; gate g: row *= 2*log2e. Bias at (quad2,j0) vs B's 1.0.
    bf16x8 wf[4][5];
    #pragma unroll
    for (int g = 0; g < 4; ++g) {
        const float sc = (g == 2) ? TWOL2E : -LOG2E;
        const int grow = g * HDIM + w * 16 + m16;
        const float* whr = W_hh + grow * HDIM;
        const float* wir = W_ih + grow * DDIM;
        #pragma unroll
        for (int q = 0; q < 4; ++q) {
            union { unsigned short u[8]; bf16x8 v; } pk;
            #pragma unroll
            for (int j = 0; j < 8; ++j)
                pk.u[j] = f2bf(sc * whr[q * 32 + quad * 8 + j]);
            wf[g][q] = pk.v;
        }
        {
            union { unsigned short u[8]; bf16x8 v; } pk;
            #pragma unroll
            for (int j = 0; j < 8; ++j) {
                float v = 0.0f;
                if (quad < 2) v = sc * wir[quad * 8 + j];
                else if (quad == 2 && j == 0) v = sc * (b_ih[grow] + b_hh[grow]);
                pk.u[j] = f2bf(v);
            }
            wf[g][4] = pk.v;
        }
    }

    uint2 cs[NSLOT];   // c-state: 4 bf16 per lane, static slot indices
    float mh[4] = {-1e30f, -1e30f, -1e30f, -1e30f};
    const int kslot = w * 2 + (quad >> 1);

    // per-node MFMA: z-chain for (jo, ps) -> acc
    auto mfma_node = [&](f32x4 (&acc)[4], int jo, int ps) {
        {
            const bf16x8 bfx = *(const bf16x8*)&xb[((jo * 4 + quad) * NSAMP + m16) * 8];
            #pragma unroll
            for (int g = 0; g < 4; ++g)
                acc[g] = __builtin_amdgcn_mfma_f32_16x16x32_bf16(
                    wf[g][4], bfx, f32x4{0.f, 0.f, 0.f, 0.f}, 0, 0, 0);
        }
        if (ps >= 0) {
            #pragma unroll
            for (int q = 0; q < 4; ++q) {
                const bf16x8 bh = *(const bf16x8*)
                    &hs[((ps * 16 + q * 4 + quad) * NSAMP + m16) * 8];
                #pragma unroll
                for (int g = 0; g < 4; ++g)
                    acc[g] = __builtin_amdgcn_mfma_f32_16x16x32_bf16(
                        wf[g][q], bh, acc[g], 0, 0, 0);
            }
        }
    };

    // fused pointwise (verified R9-R11) + publish
    auto pointwise_node = [&](f32x4 (&acc)[4], int ps, int sl) {
        float cn4[4], hn4[4];
        #pragma unroll
        for (int r = 0; r < 4; ++r) {
            float cprev = 0.0f;
            if (ps >= 0) {
                const unsigned p = (r < 2) ? cs[ps].x : cs[ps].y;
                cprev = (r & 1) ? bfhi(p) : bflo(p);
            }
            const float u  = 1.0f + __builtin_amdgcn_exp2f(acc[0][r]);
            const float q  = 1.0f + __builtin_amdgcn_exp2f(acc[1][r]);
            const float v  = 1.0f + __builtin_amdgcn_exp2f(acc[2][r]);
            const float qo = 1.0f + __builtin_amdgcn_exp2f(acc[3][r]);
            const float uv  = u * v;
            const float num = fmaf(q, v - 2.0f, cprev * uv);
            const float cn  = num * __builtin_amdgcn_rcpf(q * uv);
            const float wt  = 1.0f + __builtin_amdgcn_exp2f(TWOL2E * cn);
            const float h   = (wt - 2.0f) * __builtin_amdgcn_rcpf(qo * wt);
            cn4[r] = cn; hn4[r] = h;
            mh[r] = fmaxf(mh[r], h);
        }
        if (sl >= 0) {
            cs[sl].x = pk2(cn4[0], cn4[1]);
            cs[sl].y = pk2(cn4[2], cn4[3]);
            union { __hip_bfloat162 h2[2]; uint2 v; } hp;
            hp.h2[0] = __float22bfloat162_rn(float2{hn4[0], hn4[1]});
            hp.h2[1] = __float22bfloat162_rn(float2{hn4[2], hn4[3]});
            *(uint2*)&hs[((sl * 16 + kslot) * NSAMP + m16) * 8
                         + (quad & 1) * 4] = hp.v;
        }
    };

    #pragma unroll
    for (int d = 1; d <= 6; ++d) {
        __syncthreads();
        #pragma unroll
        for (int gi = 0; gi < GR.cnt[d]; ++gi) {
            if (GR.bar[d][gi]) __syncthreads();   // recycle barrier (constexpr)
            const int ka = GR.a[d][gi];
            const int kb = GR.b[d][gi];           // -1 = single

            f32x4 accA[4], accB[4];
            mfma_node(accA, PL2.nd[ka].jo, PL2.nd[ka].ps);
            if (kb >= 0) mfma_node(accB, PL2.nd[kb].jo, PL2.nd[kb].ps);
            pointwise_node(accA, PL2.nd[ka].ps, PL2.nd[ka].sl);
            if (kb >= 0) pointwise_node(accB, PL2.nd[kb].ps, PL2.nd[kb].sl);
        }
    }

    __syncthreads();   // h slots dead; reuse hs for epilogue
    {
        float4 v; v.x = mh[0]; v.y = mh[1]; v.z = mh[2]; v.w = mh[3];
        *(float4*)&s_maxh[m16 * HDIM + w * 16 + quad * 4] = v;
    }
    __syncthreads();

    // ---- FC1: f = t&255, sample half t>>8 (8 samples each) ----
    {
        const int f  = t & 255;
        const int sh = t >> 8;
        float a1[8];
        #pragma unroll
        for (int s = 0; s < 8; ++s) a1[s] = fc1_b[f];
        for (int k4 = 0; k4 < HDIM / 4; ++k4) {
            const float4 wv = *(const float4*)&fc1_W[f * HDIM + k4 * 4];
            #pragma unroll
            for (int s = 0; s < 8; ++s) {
                const float4 h4 = *(const float4*)&s_maxh[(sh * 8 + s) * HDIM + k4 * 4];
                a1[s] += wv.x * h4.x + wv.y * h4.y + wv.z * h4.z + wv.w * h4.w;
            }
        }
        #pragma unroll
        for (int s = 0; s < 8; ++s)
            s_fc1[(sh * 8 + s) * 256 + f] = fmaxf(a1[s], 0.0f);
    }
    __syncthreads();

    if (t < NSAMP * 10) {
        const int s = t / 10, a = t % 10;
        float acc2 = fc2_b[a];
        for (int f4 = 0; f4 < 256 / 4; ++f4) {
            const float4 wv = *(const float4*)&fc2_W[a * 256 + f4 * 4];
            const float4 v  = *(const float4*)&s_fc1[s * 256 + f4 * 4];
            acc2 += wv.x * v.x + wv.y * v.y + wv.z * v.z + wv.w * v.w;
        }
        s_logit[s * 10 + a] = acc2;
    }
    __syncthreads();

    if (t < NSAMP) {
        float m = -1e30f;
        #pragma unroll
        for (int a = 0; a < 10; ++a) m = fmaxf(m, s_logit[t * 10 + a]);
        float sum = 0.0f;
        #pragma unroll
        for (int a = 0; a < 10; ++a) sum += __expf(s_logit[t * 10 + a] - m);
        const float lse = m + __logf(sum);
        #pragma unroll
        for (int a = 0; a < 10; ++a)
            out[(s_base + t) * 10 + a] = s_logit[t * 10 + a] - lse;
    }
}

extern "C" void kernel_launch(void* const* d_in, const int* in_sizes, int n_in,
                              void* d_out, int out_size, void* d_ws, size_t ws_size,
                              hipStream_t stream)
{
    (void)d_ws; (void)ws_size; (void)n_in; (void)out_size;

    const float* x   = (const float*)d_in[0];
    const float* Wih = (const float*)d_in[1];
    const float* Whh = (const float*)d_in[2];
    const float* bih = (const float*)d_in[3];
    const float* bhh = (const float*)d_in[4];
    const float* f1w = (const float*)d_in[5];
    const float* f1b = (const float*)d_in[6];
    const float* f2w = (const float*)d_in[7];
    const float* f2b = (const float*)d_in[8];

    const int mb = in_sizes[0] / (NOBJ * DDIM);   // 8192
    dim3 grid(mb / NSAMP), block(BLOCK);
    subset_lstm_p14_kernel<<<grid, block, 0, stream>>>(
        x, Wih, Whh, bih, bhh, f1w, f1b, f2w, f2b, (float*)d_out);
}

// Round 14
// 194.797 us; speedup vs baseline: 1.0554x; 1.0044x over previous
//
#include <hip/hip_runtime.h>
#include <hip/hip_bf16.h>

#define BLOCK   512     // 8 waves; wave w owns channels w*16..w*16+15, all 4 gates
#define NSAMP   16
#define HDIM    128
#define DDIM    16
#define NOBJ    6
#define NSLOT   14

typedef __attribute__((ext_vector_type(8))) short bf16x8;
typedef __attribute__((ext_vector_type(4))) float f32x4;

constexpr int pc6(int m)  { int c = 0; for (int i = 0; i < 6; ++i) c += (m >> i) & 1; return c; }
constexpr int msb6(int m) { int b = -1; for (int i = 0; i < 6; ++i) if (m & (1 << i)) b = i; return b; }

// Compile-time BFS plan, 14-slot allocator with multi-phase recycling (verified R11/R13).
struct PNode { int jo, ps, sl; bool bar; };
struct Plan2 { PNode nd[63]; int lvlStart[8]; };
constexpr Plan2 make_plan2() {
    Plan2 P{};
    int slotOf[64] = {};
    bool busy[NSLOT] = {};
    int k = 0;
    for (int d = 1; d <= 6; ++d) {
        P.lvlStart[d] = k;
        for (int M = 1; M < 64; ++M) {               // leaves (msb==5): no slot
            if (pc6(M) != d || msb6(M) != 5) continue;
            P.nd[k].jo = 5;
            P.nd[k].ps = (d == 1) ? -1 : slotOf[M & ~(1 << 5)];
            P.nd[k].sl = -1;
            P.nd[k].bar = false;
            ++k;
        }
        int pend[20] = {}; int np = 0;
        for (int M = 1; M < 64; ++M)
            if (pc6(M) == d && msb6(M) < 5) pend[np++] = M;
        int key[20] = {};
        for (int i = 0; i < np; ++i) {
            if (d == 1) { key[i] = 0; continue; }
            const int par = pend[i] & ~(1 << msb6(pend[i]));
            int c2 = 0;
            for (int j2 = 0; j2 < np; ++j2)
                if ((pend[j2] & ~(1 << msb6(pend[j2]))) == par) ++c2;
            key[i] = c2;
        }
        for (int a = 0; a < np; ++a)
            for (int b2 = a + 1; b2 < np; ++b2)
                if (key[b2] < key[a]) {
                    int tm = key[a]; key[a] = key[b2]; key[b2] = tm;
                    tm = pend[a]; pend[a] = pend[b2]; pend[b2] = tm;
                }
        bool placed[20] = {};
        int nplaced = 0;
        bool firstPhase = true;
        while (nplaced < np) {
            bool needBar = !firstPhase;
            bool any = false;
            for (int i = 0; i < np; ++i) {
                if (placed[i]) continue;
                int fs = -1;
                for (int s = 0; s < NSLOT; ++s) if (!busy[s]) { fs = s; break; }
                if (fs < 0) break;
                const int M = pend[i]; const int hi = msb6(M);
                busy[fs] = true; slotOf[M] = fs;
                P.nd[k].jo = hi;
                P.nd[k].ps = (d == 1) ? -1 : slotOf[M & ~(1 << hi)];
                P.nd[k].sl = fs;
                P.nd[k].bar = needBar; needBar = false;
                ++k; placed[i] = true; ++nplaced; any = true;
            }
            firstPhase = false;
            if (nplaced < np) {
                if (!any) break;
                for (int M = 1; M < 64; ++M) {
                    if (pc6(M) != d - 1 || msb6(M) >= 5) continue;
                    bool allp = true;
                    for (int i = 0; i < np; ++i)
                        if (!placed[i] &&
                            ((pend[i] & ~(1 << msb6(pend[i]))) == M)) allp = false;
                    if (allp) busy[slotOf[M]] = false;
                }
            }
        }
        for (int s = 0; s < NSLOT; ++s) busy[s] = false;
        for (int M = 1; M < 64; ++M)
            if (pc6(M) == d && msb6(M) < 5) busy[slotOf[M]] = true;
    }
    P.lvlStart[7] = k;
    return P;
}
constexpr Plan2 PL2 = make_plan2();
static_assert(PL2.lvlStart[7] == 63, "plan must cover all 63 nodes");

#define LOG2E   1.44269504f
#define TWOL2E  2.88539008f
#define SLOT_SH 2048            // shorts per slot (4 KB), h and c pools

__device__ __forceinline__ unsigned short f2bf(float x) {
    union { float f; unsigned int u; } a; a.f = x;
    unsigned int r = (a.u + 0x7FFFu + ((a.u >> 16) & 1u)) >> 16;
    return (unsigned short)r;
}
__device__ __forceinline__ unsigned pk2(float a, float b) {
    union { __hip_bfloat162 h; unsigned u; } z;
    z.h = __float22bfloat162_rn(float2{a, b});
    return z.u;
}
__device__ __forceinline__ float bflo(unsigned p) {
    union { unsigned u; float f; } a; a.u = p << 16; return a.f;
}
__device__ __forceinline__ float bfhi(unsigned p) {
    union { unsigned u; float f; } a; a.u = p & 0xFFFF0000u; return a.f;
}

// h pool: hs[((slot*16 + kslot)*NSAMP + n)*8 + j] = h[ch = kslot*8+j][sample n]
//   B-frag chunk q, lane (quad,m16): kslot = q*4+quad -> 16B-aligned ds_read_b128
//   wave w writes ch = w*16+quad*4+r at kslot = w*2+(quad>>1), j = (quad&1)*4+r
// c pool: csb[((slot*32 + w*4+quad)*NSAMP + n)*4 + r], bf16 (b64/lane, conflict-free)

__global__ __launch_bounds__(BLOCK)
__attribute__((amdgpu_waves_per_eu(2, 4)))   // R11/R13-verified: VGPR cap 128
void subset_lstm_skew_kernel(
    const float* __restrict__ x_input,
    const float* __restrict__ W_ih,
    const float* __restrict__ W_hh,
    const float* __restrict__ b_ih,
    const float* __restrict__ b_hh,
    const float* __restrict__ fc1_W,
    const float* __restrict__ fc1_b,
    const float* __restrict__ fc2_W,
    const float* __restrict__ fc2_b,
    float* __restrict__ out)
{
    __shared__ __align__(16) unsigned short hs [NSLOT * SLOT_SH];       // 56 KB
    __shared__ __align__(16) unsigned short csb[NSLOT * SLOT_SH];       // 56 KB
    __shared__ __align__(16) unsigned short xb[NOBJ * 4 * NSAMP * 8];   // 6 KB
    float* s_maxh  = (float*)hs;                 // 8 KB  (post-LSTM alias)
    float* s_fc1   = (float*)(hs + 4096);        // 16 KB (post-LSTM alias)
    float* s_logit = (float*)xb;

    const int t      = threadIdx.x;
    const int w      = t >> 6;
    const int lane   = t & 63;
    const int quad   = lane >> 4;
    const int m16    = lane & 15;
    const int s_base = blockIdx.x * NSAMP;

    // ---- x B-chunks: xb[obj][quad'][n][j]; quad2 j0 = 1.0 (bias lane), quad3 zero ----
    for (int idx = t; idx < NOBJ * 4 * NSAMP * 8; idx += BLOCK) {
        const int j = idx & 7, n = (idx >> 3) & 15, q = (idx >> 7) & 3, obj = idx >> 9;
        float v;
        if (q < 2) v = x_input[(s_base + n) * (NOBJ * DDIM) + obj * DDIM + q * 8 + j];
        else       v = (q == 2 && j == 0) ? 1.0f : 0.0f;
        xb[idx] = f2bf(v);
    }

    // ---- persistent A-frags wf[gate][chunk], PRE-SCALED (verified R8-R13) ----
    bf16x8 wf[4][5];
    #pragma unroll
    for (int g = 0; g < 4; ++g) {
        const float sc = (g == 2) ? TWOL2E : -LOG2E;
        const int grow = g * HDIM + w * 16 + m16;
        const float* whr = W_hh + grow * HDIM;
        const float* wir = W_ih + grow * DDIM;
        #pragma unroll
        for (int q = 0; q < 4; ++q) {
            union { unsigned short u[8]; bf16x8 v; } pk;
            #pragma unroll
            for (int j = 0; j < 8; ++j)
                pk.u[j] = f2bf(sc * whr[q * 32 + quad * 8 + j]);
            wf[g][q] = pk.v;
        }
        {
            union { unsigned short u[8]; bf16x8 v; } pk;
            #pragma unroll
            for (int j = 0; j < 8; ++j) {
                float v = 0.0f;
                if (quad < 2) v = sc * wir[quad * 8 + j];
                else if (quad == 2 && j == 0) v = sc * (b_ih[grow] + b_hh[grow]);
                pk.u[j] = f2bf(v);
            }
            wf[g][4] = pk.v;
        }
    }

    float mh[4] = {-1e30f, -1e30f, -1e30f, -1e30f};
    const int kslot = w * 2 + (quad >> 1);
    unsigned short* const c_lane = &csb[(((w * 4 + quad) * NSAMP) + m16) * 4];

    // GEMM for node (jo, ps): also prefetches parent's c (consumed next interval)
    auto mfma_node = [&](f32x4 (&acc)[4], uint2& cpk, int jo, int ps) {
        cpk.x = 0u; cpk.y = 0u;
        if (ps >= 0) cpk = *(const uint2*)(c_lane + ps * SLOT_SH);
        {
            const bf16x8 bfx = *(const bf16x8*)&xb[((jo * 4 + quad) * NSAMP + m16) * 8];
            #pragma unroll
            for (int g = 0; g < 4; ++g)
                acc[g] = __builtin_amdgcn_mfma_f32_16x16x32_bf16(
                    wf[g][4], bfx, f32x4{0.f, 0.f, 0.f, 0.f}, 0, 0, 0);
        }
        if (ps >= 0) {
            #pragma unroll
            for (int q = 0; q < 4; ++q) {
                const bf16x8 bh = *(const bf16x8*)
                    &hs[((ps * 16 + q * 4 + quad) * NSAMP + m16) * 8];
                #pragma unroll
                for (int g = 0; g < 4; ++g)
                    acc[g] = __builtin_amdgcn_mfma_f32_16x16x32_bf16(
                        wf[g][q], bh, acc[g], 0, 0, 0);
            }
        }
    };

    // fused pointwise (verified R9-R13) on a PREVIOUS interval's acc + publish
    auto pointwise_node = [&](const f32x4 (&acc)[4], uint2 cpk, int sl) {
        float cn4[4], hn4[4];
        #pragma unroll
        for (int r = 0; r < 4; ++r) {
            const unsigned p = (r < 2) ? cpk.x : cpk.y;
            const float cprev = (r & 1) ? bfhi(p) : bflo(p);
            const float u  = 1.0f + __builtin_amdgcn_exp2f(acc[0][r]);
            const float q  = 1.0f + __builtin_amdgcn_exp2f(acc[1][r]);
            const float v  = 1.0f + __builtin_amdgcn_exp2f(acc[2][r]);
            const float qo = 1.0f + __builtin_amdgcn_exp2f(acc[3][r]);
            const float uv  = u * v;
            const float num = fmaf(q, v - 2.0f, cprev * uv);
            const float cn  = num * __builtin_amdgcn_rcpf(q * uv);
            const float wt  = 1.0f + __builtin_amdgcn_exp2f(TWOL2E * cn);
            const float h   = (wt - 2.0f) * __builtin_amdgcn_rcpf(qo * wt);
            cn4[r] = cn; hn4[r] = h;
            mh[r] = fmaxf(mh[r], h);
        }
        if (sl >= 0) {
            uint2 cw; cw.x = pk2(cn4[0], cn4[1]); cw.y = pk2(cn4[2], cn4[3]);
            *(uint2*)(c_lane + sl * SLOT_SH) = cw;
            uint2 hw; hw.x = pk2(hn4[0], hn4[1]); hw.y = pk2(hn4[2], hn4[3]);
            *(uint2*)&hs[((sl * 16 + kslot) * NSAMP + m16) * 8 + (quad & 1) * 4] = hw;
        }
    };

    #pragma unroll
    for (int d = 1; d <= 6; ++d) {
        __syncthreads();
        const int kBeg = PL2.lvlStart[d];
        const int kEnd = PL2.lvlStart[d + 1];
        f32x4 accP[2][4];   // ping-pong, parity = (k - kBeg) & 1 (constexpr after unroll)
        uint2 cpP[2];
        #pragma unroll
        for (int k = kBeg; k < kEnd; ++k) {
            const int par = (k - kBeg) & 1;
            if (PL2.nd[k].bar) __syncthreads();   // recycle barrier (constexpr)
            mfma_node(accP[par], cpP[par], PL2.nd[k].jo, PL2.nd[k].ps);
            if (k > kBeg)
                pointwise_node(accP[par ^ 1], cpP[par ^ 1], PL2.nd[k - 1].sl);
        }
        // flush the pending node before the next level barrier
        const int lpar = (kEnd - 1 - kBeg) & 1;
        pointwise_node(accP[lpar], cpP[lpar], PL2.nd[kEnd - 1].sl);
    }

    __syncthreads();   // pools dead; reuse hs for epilogue
    {
        float4 v; v.x = mh[0]; v.y = mh[1]; v.z = mh[2]; v.w = mh[3];
        *(float4*)&s_maxh[m16 * HDIM + w * 16 + quad * 4] = v;
    }
    __syncthreads();

    // ---- FC1: f = t&255, sample half t>>8 (8 samples each) ----
    {
        const int f  = t & 255;
        const int sh = t >> 8;
        float a1[8];
        #pragma unroll
        for (int s = 0; s < 8; ++s) a1[s] = fc1_b[f];
        for (int k4 = 0; k4 < HDIM / 4; ++k4) {
            const float4 wv = *(const float4*)&fc1_W[f * HDIM + k4 * 4];
            #pragma unroll
            for (int s = 0; s < 8; ++s) {
                const float4 h4 = *(const float4*)&s_maxh[(sh * 8 + s) * HDIM + k4 * 4];
                a1[s] += wv.x * h4.x + wv.y * h4.y + wv.z * h4.z + wv.w * h4.w;
            }
        }
        #pragma unroll
        for (int s = 0; s < 8; ++s)
            s_fc1[(sh * 8 + s) * 256 + f] = fmaxf(a1[s], 0.0f);
    }
    __syncthreads();

    if (t < NSAMP * 10) {
        const int s = t / 10, a = t % 10;
        float acc2 = fc2_b[a];
        for (int f4 = 0; f4 < 256 / 4; ++f4) {
            const float4 wv = *(const float4*)&fc2_W[a * 256 + f4 * 4];
            const float4 v  = *(const float4*)&s_fc1[s * 256 + f4 * 4];
            acc2 += wv.x * v.x + wv.y * v.y + wv.z * v.z + wv.w * v.w;
        }
        s_logit[s * 10 + a] = acc2;
    }
    __syncthreads();

    if (t < NSAMP) {
        float m = -1e30f;
        #pragma unroll
        for (int a = 0; a < 10; ++a) m = fmaxf(m, s_logit[t * 10 + a]);
        float sum = 0.0f;
        #pragma unroll
        for (int a = 0; a < 10; ++a) sum += __expf(s_logit[t * 10 + a] - m);
        const float lse = m + __logf(sum);
        #pragma unroll
        for (int a = 0; a < 10; ++a)
            out[(s_base + t) * 10 + a] = s_logit[t * 10 + a] - lse;
    }
}

extern "C" void kernel_launch(void* const* d_in, const int* in_sizes, int n_in,
                              void* d_out, int out_size, void* d_ws, size_t ws_size,
                              hipStream_t stream)
{
    (void)d_ws; (void)ws_size; (void)n_in; (void)out_size;

    const float* x   = (const float*)d_in[0];
    const float* Wih = (const float*)d_in[1];
    const float* Whh = (const float*)d_in[2];
    const float* bih = (const float*)d_in[3];
    const float* bhh = (const float*)d_in[4];
    const float* f1w = (const float*)d_in[5];
    const float* f1b = (const float*)d_in[6];
    const float* f2w = (const float*)d_in[7];
    const float* f2b = (const float*)d_in[8];

    const int mb = in_sizes[0] / (NOBJ * DDIM);   // 8192
    dim3 grid(mb / NSAMP), block(BLOCK);
    subset_lstm_skew_kernel<<<grid, block, 0, stream>>>(
        x, Wih, Whh, bih, bhh, f1w, f1b, f2w, f2b, (float*)d_out);
}